// Round 6
// baseline (354.790 us; speedup 1.0000x reference)
//
#include <hip/hip_runtime.h>
#include <hip/hip_bf16.h>

#define NNODES 50000
#define NEDGES 600000
#define DIM    128
#define NLAYERS 3
#define NCLS   10
#define NGRAPH 256
#define BN_EPS 1e-5f

#define SCAN_BLK 256
#define NSB ((NNODES + SCAN_BLK - 1) / SCAN_BLK)   // 196 blocks

typedef __attribute__((ext_vector_type(8))) short bf16x8;   // 8 bf16 = 4 VGPR
typedef __attribute__((ext_vector_type(4))) float f32x4;

static __device__ __forceinline__ unsigned short f2b(float f) {
    union { __hip_bfloat16 h; unsigned short u; } c;
    c.h = __float2bfloat16(f);
    return c.u;
}
static __device__ __forceinline__ float b2f(short s) {
    return __uint_as_float(((unsigned)(unsigned short)s) << 16);
}
static __device__ __forceinline__ unsigned pack2(float a, float b) {
    return (unsigned)f2b(a) | ((unsigned)f2b(b) << 16);
}

// ---------------- CSR build ----------------

__global__ void count_deg(const int* __restrict__ dst, int* __restrict__ deg, int E) {
    int e = blockIdx.x * blockDim.x + threadIdx.x;
    if (e < E) atomicAdd(&deg[dst[e]], 1);
}

// 3-phase device-wide exclusive scan of deg -> off/cursor.
__global__ __launch_bounds__(SCAN_BLK) void partial_sum(const int* __restrict__ deg,
                                                        int* __restrict__ part, int n) {
    int t = threadIdx.x;
    int i = blockIdx.x * SCAN_BLK + t;
    int v = (i < n) ? deg[i] : 0;
#pragma unroll
    for (int o = 32; o > 0; o >>= 1) v += __shfl_down(v, o, 64);
    __shared__ int s[SCAN_BLK / 64];
    if ((t & 63) == 0) s[t >> 6] = v;
    __syncthreads();
    if (t == 0) {
        int sum = 0;
#pragma unroll
        for (int w = 0; w < SCAN_BLK / 64; ++w) sum += s[w];
        part[blockIdx.x] = sum;
    }
}

__global__ __launch_bounds__(256) void scan_partials(int* __restrict__ part, int nb) {
    __shared__ int s[256];
    int t = threadIdx.x;
    int v = (t < nb) ? part[t] : 0;
    s[t] = v;
    __syncthreads();
    for (int o = 1; o < 256; o <<= 1) {
        int u = (t >= o) ? s[t - o] : 0;
        __syncthreads();
        s[t] += u;
        __syncthreads();
    }
    if (t < nb) part[t] = (t == 0) ? 0 : s[t - 1];
}

__global__ __launch_bounds__(SCAN_BLK) void emit_offsets(const int* __restrict__ deg,
                                                         const int* __restrict__ part,
                                                         int* __restrict__ off,
                                                         int* __restrict__ cursor, int n) {
    __shared__ int s[SCAN_BLK];
    int t = threadIdx.x;
    int i = blockIdx.x * SCAN_BLK + t;
    int v = (i < n) ? deg[i] : 0;
    s[t] = v;
    __syncthreads();
    for (int o = 1; o < SCAN_BLK; o <<= 1) {
        int u = (t >= o) ? s[t - o] : 0;
        __syncthreads();
        s[t] += u;
        __syncthreads();
    }
    if (i < n) {
        int excl = part[blockIdx.x] + s[t] - v;
        off[i] = excl;
        cursor[i] = excl;
    }
}

// one 8B store per edge: (src, w_bits) — halves scatter line traffic vs two arrays
__global__ void fill_csr(const int* __restrict__ src, const int* __restrict__ dst,
                         const float* __restrict__ emask,
                         int* __restrict__ cursor,
                         uint2* __restrict__ csr, int E) {
    int e = blockIdx.x * blockDim.x + threadIdx.x;
    if (e < E) {
        int d = dst[e];
        int p = atomicAdd(&cursor[d], 1);
        csr[p] = make_uint2((unsigned)src[e], __float_as_uint(emask[e]));
    }
}

// ---------------- prep: BN fold, W transpose->bf16, x->bf16 ----------------

__global__ void prep_bn(const float* __restrict__ gamma, const float* __restrict__ beta,
                        const float* __restrict__ mean, const float* __restrict__ var,
                        const float* __restrict__ b1,
                        float* __restrict__ colA, float* __restrict__ colB, int n) {
    int i = blockIdx.x * blockDim.x + threadIdx.x;
    if (i < n) {
        float A = gamma[i] * rsqrtf(var[i] + BN_EPS);
        colA[i] = A;
        colB[i] = beta[i] - mean[i] * A + b1[i] * A;
    }
}

// W[l][k][n] f32  ->  WT[l][n][k] bf16
__global__ void prep_wt(const float* __restrict__ W1, const float* __restrict__ W2,
                        unsigned short* __restrict__ W1T, unsigned short* __restrict__ W2T, int total) {
    int i = blockIdx.x * blockDim.x + threadIdx.x;
    if (i < total) {
        int l  = i / (DIM * DIM);
        int r  = i - l * DIM * DIM;
        int nn = r / DIM;
        int kk = r - nn * DIM;
        int sidx = l * DIM * DIM + kk * DIM + nn;
        W1T[i] = f2b(W1[sidx]);
        W2T[i] = f2b(W2[sidx]);
    }
}

__global__ void conv_x(const float* __restrict__ x, unsigned short* __restrict__ xb, int n4) {
    int i = blockIdx.x * blockDim.x + threadIdx.x;
    if (i < n4) {
        float4 v = ((const float4*)x)[i];
        unsigned lo = pack2(v.x, v.y);
        unsigned hi = pack2(v.z, v.w);
        ((uint2*)xb)[i] = make_uint2(lo, hi);
    }
}

// ---------------- gathers: 4 nodes/wave, 16 lanes/node, 16B row chunks ----------------
// One global_load_dwordx4 fetches 4 different neighbor rows (one per quarter-wave).
// Degree divergence across the 4 nodes handled by exec mask.

__global__ __launch_bounds__(256) void gather0(const unsigned short* __restrict__ xb,
                                               const int* __restrict__ off, const int* __restrict__ deg,
                                               const uint2* __restrict__ csr,
                                               const int* __restrict__ snmask,
                                               unsigned short* __restrict__ X, int n) {
    int wave = (blockIdx.x * blockDim.x + threadIdx.x) >> 6;
    int lane = threadIdx.x & 63;
    int q    = lane >> 4;       // quarter 0..3
    int l16  = lane & 15;
    int node = wave * 4 + q;
    bool valid = node < n;
    int nd   = valid ? node : (n - 1);
    int base = off[nd];
    int dg   = valid ? deg[nd] : 0;

    float acc[8];
#pragma unroll
    for (int i = 0; i < 8; ++i) acc[i] = 0.f;

    for (int j = 0; j < dg; ++j) {
        uint2 sw = csr[base + j];                 // same addr within quarter -> broadcast
        int s    = (int)sw.x;
        float w  = __uint_as_float(sw.y);
        bf16x8 v = *(const bf16x8*)&xb[(long)s * DIM + l16 * 8];
#pragma unroll
        for (int i = 0; i < 8; ++i) acc[i] = fmaf(w, b2f(v[i]), acc[i]);
    }

    if (valid) {
        bf16x8 res = *(const bf16x8*)&xb[(long)node * DIM + l16 * 8];  // self
        if (snmask[node]) {
#pragma unroll
            for (int i = 0; i < 8; ++i) res[i] = (short)f2b(acc[i]);
        }
        *(bf16x8*)&X[(long)node * DIM + l16 * 8] = res;
    }
}

__global__ __launch_bounds__(256) void gatherL(const unsigned short* __restrict__ X,
                                               const int* __restrict__ off, const int* __restrict__ deg,
                                               const uint2* __restrict__ csr,
                                               unsigned short* __restrict__ H, int n) {
    int wave = (blockIdx.x * blockDim.x + threadIdx.x) >> 6;
    int lane = threadIdx.x & 63;
    int q    = lane >> 4;
    int l16  = lane & 15;
    int node = wave * 4 + q;
    bool valid = node < n;
    int nd   = valid ? node : (n - 1);
    int base = off[nd];
    int dg   = valid ? deg[nd] : 0;

    float acc[8];
    {   // GIN eps=0 self term
        bf16x8 self = *(const bf16x8*)&X[(long)nd * DIM + l16 * 8];
#pragma unroll
        for (int i = 0; i < 8; ++i) acc[i] = b2f(self[i]);
    }

    for (int j = 0; j < dg; ++j) {
        uint2 sw = csr[base + j];
        int s    = (int)sw.x;
        bf16x8 v = *(const bf16x8*)&X[(long)s * DIM + l16 * 8];
#pragma unroll
        for (int i = 0; i < 8; ++i) acc[i] += b2f(v[i]);
    }

    if (valid) {
        bf16x8 res;
#pragma unroll
        for (int i = 0; i < 8; ++i) res[i] = (short)f2b(acc[i]);
        *(bf16x8*)&H[(long)node * DIM + l16 * 8] = res;
    }
}

// ---------------- MFMA MLP: H(bf16) -> Lin1+BN+ReLU -> Lin2+ReLU -> X(bf16) ----------------
// 512 threads = 8 waves. Block: 64 rows x 128 cols. Wave (wr=wid>>2, wc=wid&3): rows wr*32..+31, cols wc*32..+31.
// mfma_f32_16x16x32_bf16 layouts (gfx950, m89-verified):
//   A: lane l elem j -> A[row = l&15][k = (l>>4)*8 + j]
//   B: lane l elem j -> B[k = (l>>4)*8 + j][col = l&15]   (loaded from WT[n][k], 16B contiguous)
//   D: lane l reg  v -> D[row = (l>>4)*4 + v][col = l&15]
#define HPITCH 136   // bf16 elems; 272B rows: 16B-aligned, 2-way LDS aliasing only

__global__ __launch_bounds__(512) void mlp_mfma(const unsigned short* __restrict__ H,
                                                unsigned short* __restrict__ X,
                                                const unsigned short* __restrict__ W1T,
                                                const unsigned short* __restrict__ W2T,
                                                const float* __restrict__ colA, const float* __restrict__ colB,
                                                const float* __restrict__ b2, int n) {
    __shared__ unsigned short h_t[64 * HPITCH];
    int t    = threadIdx.x;
    int wid  = t >> 6;
    int lane = t & 63;
    int wr   = wid >> 2;          // 0..1
    int wc   = wid & 3;           // 0..3
    int c0   = wc * 32;
    int lm   = lane & 15;
    int lk   = (lane >> 4) * 8;
    int row0 = blockIdx.x * 64 + wr * 32;

    // ---- A fragments from global H (rows clamped for tail block) ----
    bf16x8 a[2][4];
#pragma unroll
    for (int rs = 0; rs < 2; ++rs)
#pragma unroll
        for (int ks = 0; ks < 4; ++ks) {
            int r = row0 + rs * 16 + lm;
            if (r >= n) r = n - 1;
            a[rs][ks] = *(const bf16x8*)&H[(long)r * DIM + ks * 32 + lk];
        }

    // ---- B fragments for W1 ----
    bf16x8 b1[2][4];
#pragma unroll
    for (int cs = 0; cs < 2; ++cs)
#pragma unroll
        for (int ks = 0; ks < 4; ++ks) {
            int col = c0 + cs * 16 + lm;
            b1[cs][ks] = *(const bf16x8*)&W1T[col * DIM + ks * 32 + lk];
        }

    f32x4 acc[2][2];
    f32x4 z = {0.f, 0.f, 0.f, 0.f};
#pragma unroll
    for (int rs = 0; rs < 2; ++rs)
#pragma unroll
        for (int cs = 0; cs < 2; ++cs) acc[rs][cs] = z;

#pragma unroll
    for (int ks = 0; ks < 4; ++ks)
#pragma unroll
        for (int rs = 0; rs < 2; ++rs)
#pragma unroll
            for (int cs = 0; cs < 2; ++cs)
                acc[rs][cs] = __builtin_amdgcn_mfma_f32_16x16x32_bf16(a[rs][ks], b1[cs][ks], acc[rs][cs], 0, 0, 0);

    // ---- epilogue 1: affine(BN)+ReLU -> bf16 -> LDS ----
#pragma unroll
    for (int rs = 0; rs < 2; ++rs)
#pragma unroll
        for (int cs = 0; cs < 2; ++cs) {
            int colv = c0 + cs * 16 + lm;
            float cA = colA[colv], cB = colB[colv];
            int rbase = wr * 32 + rs * 16 + (lane >> 4) * 4;
            f32x4 av = acc[rs][cs];
#pragma unroll
            for (int v = 0; v < 4; ++v) {
                float h = fmaxf(fmaf(av[v], cA, cB), 0.f);
                h_t[(rbase + v) * HPITCH + colv] = f2b(h);
            }
        }
    __syncthreads();

    // ---- A2 fragments from LDS, B2 fragments from global ----
    bf16x8 a2[2][4];
#pragma unroll
    for (int rs = 0; rs < 2; ++rs)
#pragma unroll
        for (int ks = 0; ks < 4; ++ks)
            a2[rs][ks] = *(const bf16x8*)&h_t[(wr * 32 + rs * 16 + lm) * HPITCH + ks * 32 + lk];

    bf16x8 b2f[2][4];
#pragma unroll
    for (int cs = 0; cs < 2; ++cs)
#pragma unroll
        for (int ks = 0; ks < 4; ++ks) {
            int col = c0 + cs * 16 + lm;
            b2f[cs][ks] = *(const bf16x8*)&W2T[col * DIM + ks * 32 + lk];
        }

#pragma unroll
    for (int rs = 0; rs < 2; ++rs)
#pragma unroll
        for (int cs = 0; cs < 2; ++cs) acc[rs][cs] = z;

#pragma unroll
    for (int ks = 0; ks < 4; ++ks)
#pragma unroll
        for (int rs = 0; rs < 2; ++rs)
#pragma unroll
            for (int cs = 0; cs < 2; ++cs)
                acc[rs][cs] = __builtin_amdgcn_mfma_f32_16x16x32_bf16(a2[rs][ks], b2f[cs][ks], acc[rs][cs], 0, 0, 0);

    __syncthreads();   // all h_t reads done before overwrite

    // ---- epilogue 2: +bias, ReLU -> bf16 -> LDS ----
#pragma unroll
    for (int rs = 0; rs < 2; ++rs)
#pragma unroll
        for (int cs = 0; cs < 2; ++cs) {
            int colv = c0 + cs * 16 + lm;
            float bb = b2[colv];
            int rbase = wr * 32 + rs * 16 + (lane >> 4) * 4;
            f32x4 av = acc[rs][cs];
#pragma unroll
            for (int v = 0; v < 4; ++v) {
                float h = fmaxf(av[v] + bb, 0.f);
                h_t[(rbase + v) * HPITCH + colv] = f2b(h);
            }
        }
    __syncthreads();

    // ---- coalesced copy-out: 64 rows, 8 threads/row, 16 elems (32B) per thread ----
    {
        int row = t >> 3;
        int ch  = (t & 7) * 16;
        int gr  = blockIdx.x * 64 + row;
        if (gr < n) {
            *(bf16x8*)&X[(long)gr * DIM + ch]     = *(const bf16x8*)&h_t[row * HPITCH + ch];
            *(bf16x8*)&X[(long)gr * DIM + ch + 8] = *(const bf16x8*)&h_t[row * HPITCH + ch + 8];
        }
    }
}

// ---------------- pool (batch sorted -> run-accumulate) ----------------

__global__ __launch_bounds__(128) void pool_kernel(const unsigned short* __restrict__ X,
                                                   const int* __restrict__ batch,
                                                   float* __restrict__ POOL, int n) {
    int c  = threadIdx.x;
    int n0 = blockIdx.x * 128;
    if (n0 >= n) return;
    int n1 = n0 + 128; if (n1 > n) n1 = n;
    int gcur = batch[n0];
    float acc = 0.f;
    for (int i = n0; i < n1; ++i) {
        int g = batch[i];
        if (g != gcur) {
            atomicAdd(&POOL[(long)gcur * DIM + c], acc);
            acc = 0.f; gcur = g;
        }
        acc += __uint_as_float(((unsigned)X[(long)i * DIM + c]) << 16);
    }
    atomicAdd(&POOL[(long)gcur * DIM + c], acc);
}

// ---------------- final head ----------------

__global__ __launch_bounds__(128) void final_mlp(const float* __restrict__ POOL,
                                                 const float* __restrict__ Wf1, const float* __restrict__ bf1,
                                                 const float* __restrict__ Wf2, const float* __restrict__ bf2,
                                                 float* __restrict__ out) {
    int g = blockIdx.x;
    int t = threadIdx.x;
    __shared__ float p[128];
    __shared__ float h[128];
    p[t] = POOL[(long)g * DIM + t];
    __syncthreads();
    float acc = bf1[t];
#pragma unroll 8
    for (int k = 0; k < DIM; ++k) acc = fmaf(p[k], Wf1[k * DIM + t], acc);
    h[t] = fmaxf(acc, 0.f);
    __syncthreads();
    if (t < NCLS) {
        float acc2 = bf2[t];
#pragma unroll 8
        for (int k = 0; k < DIM; ++k) acc2 = fmaf(h[k], Wf2[k * NCLS + t], acc2);
        out[(long)g * NCLS + t] = acc2;
    }
}

// ---------------- launch ----------------

extern "C" void kernel_launch(void* const* d_in, const int* in_sizes, int n_in,
                              void* d_out, int out_size, void* d_ws, size_t ws_size,
                              hipStream_t stream) {
    const float* x      = (const float*)d_in[0];
    const int*   ei     = (const int*)d_in[1];
    const int*   snmask = (const int*)d_in[2];
    const float* emask  = (const float*)d_in[3];
    const int*   batch  = (const int*)d_in[4];
    const float* Ws1    = (const float*)d_in[5];
    const float* bs1    = (const float*)d_in[6];
    const float* gamma  = (const float*)d_in[7];
    const float* beta   = (const float*)d_in[8];
    const float* mean   = (const float*)d_in[9];
    const float* var    = (const float*)d_in[10];
    const float* Ws2    = (const float*)d_in[11];
    const float* bs2    = (const float*)d_in[12];
    const float* Wf1    = (const float*)d_in[13];
    const float* bf1    = (const float*)d_in[14];
    const float* Wf2    = (const float*)d_in[15];
    const float* bf2    = (const float*)d_in[16];
    float* out = (float*)d_out;

    const int* srcp = ei;
    const int* dstp = ei + NEDGES;

    char* ws = (char*)d_ws;
    size_t o = 0;
    auto alloc = [&](size_t bytes) -> void* {
        void* p = ws + o;
        o = (o + bytes + 255) & ~(size_t)255;
        return p;
    };
    unsigned short* XB  = (unsigned short*)alloc((size_t)NNODES * DIM * 2);
    unsigned short* X   = (unsigned short*)alloc((size_t)NNODES * DIM * 2);
    unsigned short* H   = (unsigned short*)alloc((size_t)NNODES * DIM * 2);
    int*   deg     = (int*)alloc((size_t)NNODES * 4);
    int*   off     = (int*)alloc((size_t)NNODES * 4);
    int*   cursor  = (int*)alloc((size_t)NNODES * 4);
    int*   part    = (int*)alloc((size_t)NSB * 4);
    uint2* csr     = (uint2*)alloc((size_t)NEDGES * 8);
    float* colA    = (float*)alloc((size_t)NLAYERS * DIM * 4);
    float* colB    = (float*)alloc((size_t)NLAYERS * DIM * 4);
    unsigned short* W1T = (unsigned short*)alloc((size_t)NLAYERS * DIM * DIM * 2);
    unsigned short* W2T = (unsigned short*)alloc((size_t)NLAYERS * DIM * DIM * 2);
    float* POOL    = (float*)alloc((size_t)NGRAPH * DIM * 4);

    (void)hipMemsetAsync(deg, 0, (size_t)NNODES * 4, stream);
    (void)hipMemsetAsync(POOL, 0, (size_t)NGRAPH * DIM * 4, stream);

    count_deg<<<(NEDGES + 255) / 256, 256, 0, stream>>>(dstp, deg, NEDGES);
    partial_sum<<<NSB, SCAN_BLK, 0, stream>>>(deg, part, NNODES);
    scan_partials<<<1, 256, 0, stream>>>(part, NSB);
    emit_offsets<<<NSB, SCAN_BLK, 0, stream>>>(deg, part, off, cursor, NNODES);
    fill_csr<<<(NEDGES + 255) / 256, 256, 0, stream>>>(srcp, dstp, emask, cursor, csr, NEDGES);
    prep_bn<<<(NLAYERS * DIM + 255) / 256, 256, 0, stream>>>(gamma, beta, mean, var, bs1, colA, colB, NLAYERS * DIM);
    prep_wt<<<(NLAYERS * DIM * DIM + 255) / 256, 256, 0, stream>>>(Ws1, Ws2, W1T, W2T, NLAYERS * DIM * DIM);
    conv_x<<<(NNODES * DIM / 4 + 255) / 256, 256, 0, stream>>>(x, XB, NNODES * DIM / 4);

    const int nWaves = (NNODES + 3) / 4;                       // 4 nodes per wave
    const int gatherBlocks = (nWaves * 64 + 255) / 256;
    gather0<<<gatherBlocks, 256, 0, stream>>>(XB, off, deg, csr, snmask, X, NNODES);

    const int mlpBlocks = (NNODES + 63) / 64;
    for (int l = 0; l < NLAYERS; ++l) {
        gatherL<<<gatherBlocks, 256, 0, stream>>>(X, off, deg, csr, H, NNODES);
        mlp_mfma<<<mlpBlocks, 512, 0, stream>>>(H, X,
                                                W1T + (size_t)l * DIM * DIM,
                                                W2T + (size_t)l * DIM * DIM,
                                                colA + (size_t)l * DIM,
                                                colB + (size_t)l * DIM,
                                                bs2 + (size_t)l * DIM, NNODES);
    }

    pool_kernel<<<(NNODES + 127) / 128, 128, 0, stream>>>(X, batch, POOL, NNODES);
    final_mlp<<<NGRAPH, 128, 0, stream>>>(POOL, Wf1, bf1, Wf2, bf2, out);
}

// Round 7
// 320.653 us; speedup vs baseline: 1.1065x; 1.1065x over previous
//
#include <hip/hip_runtime.h>
#include <hip/hip_bf16.h>

#define NNODES 50000
#define NEDGES 600000
#define DIM    128
#define NLAYERS 3
#define NCLS   10
#define NGRAPH 256
#define BN_EPS 1e-5f

#define SCAN_BLK 256
#define NSB ((NNODES + SCAN_BLK - 1) / SCAN_BLK)   // 196 blocks

typedef __attribute__((ext_vector_type(8))) short bf16x8;   // 8 bf16 = 4 VGPR
typedef __attribute__((ext_vector_type(4))) float f32x4;

static __device__ __forceinline__ unsigned short f2b(float f) {
    union { __hip_bfloat16 h; unsigned short u; } c;
    c.h = __float2bfloat16(f);
    return c.u;
}
static __device__ __forceinline__ float b2f(short s) {
    return __uint_as_float(((unsigned)(unsigned short)s) << 16);
}
static __device__ __forceinline__ unsigned pack2(float a, float b) {
    return (unsigned)f2b(a) | ((unsigned)f2b(b) << 16);
}

// ---------------- workspace zeroing (replaces hipMemsetAsync: runtime fill kernel
// was 41 us/dispatch latency-bound; this is ~2 us) ----------------
__global__ __launch_bounds__(256) void zero_bufs(int4* __restrict__ a, int na,
                                                 int4* __restrict__ b, int nb) {
    int i = blockIdx.x * 256 + threadIdx.x;
    int4 z = make_int4(0, 0, 0, 0);
    if (i < na) a[i] = z;
    if (i < nb) b[i] = z;
}

// ---------------- CSR build ----------------

__global__ void count_deg(const int* __restrict__ dst, int* __restrict__ deg, int E) {
    int e = blockIdx.x * blockDim.x + threadIdx.x;
    if (e < E) atomicAdd(&deg[dst[e]], 1);
}

// 3-phase device-wide exclusive scan of deg -> off/cursor.
__global__ __launch_bounds__(SCAN_BLK) void partial_sum(const int* __restrict__ deg,
                                                        int* __restrict__ part, int n) {
    int t = threadIdx.x;
    int i = blockIdx.x * SCAN_BLK + t;
    int v = (i < n) ? deg[i] : 0;
#pragma unroll
    for (int o = 32; o > 0; o >>= 1) v += __shfl_down(v, o, 64);
    __shared__ int s[SCAN_BLK / 64];
    if ((t & 63) == 0) s[t >> 6] = v;
    __syncthreads();
    if (t == 0) {
        int sum = 0;
#pragma unroll
        for (int w = 0; w < SCAN_BLK / 64; ++w) sum += s[w];
        part[blockIdx.x] = sum;
    }
}

__global__ __launch_bounds__(256) void scan_partials(int* __restrict__ part, int nb) {
    __shared__ int s[256];
    int t = threadIdx.x;
    int v = (t < nb) ? part[t] : 0;
    s[t] = v;
    __syncthreads();
    for (int o = 1; o < 256; o <<= 1) {
        int u = (t >= o) ? s[t - o] : 0;
        __syncthreads();
        s[t] += u;
        __syncthreads();
    }
    if (t < nb) part[t] = (t == 0) ? 0 : s[t - 1];
}

__global__ __launch_bounds__(SCAN_BLK) void emit_offsets(const int* __restrict__ deg,
                                                         const int* __restrict__ part,
                                                         int* __restrict__ off,
                                                         int* __restrict__ cursor, int n) {
    __shared__ int s[SCAN_BLK];
    int t = threadIdx.x;
    int i = blockIdx.x * SCAN_BLK + t;
    int v = (i < n) ? deg[i] : 0;
    s[t] = v;
    __syncthreads();
    for (int o = 1; o < SCAN_BLK; o <<= 1) {
        int u = (t >= o) ? s[t - o] : 0;
        __syncthreads();
        s[t] += u;
        __syncthreads();
    }
    if (i < n) {
        int excl = part[blockIdx.x] + s[t] - v;
        off[i] = excl;
        cursor[i] = excl;
    }
}

// one 8B store per edge: (src, w_bits) — halves scatter line traffic vs two arrays
__global__ void fill_csr(const int* __restrict__ src, const int* __restrict__ dst,
                         const float* __restrict__ emask,
                         int* __restrict__ cursor,
                         uint2* __restrict__ csr, int E) {
    int e = blockIdx.x * blockDim.x + threadIdx.x;
    if (e < E) {
        int d = dst[e];
        int p = atomicAdd(&cursor[d], 1);
        csr[p] = make_uint2((unsigned)src[e], __float_as_uint(emask[e]));
    }
}

// ---------------- prep: BN fold, W transpose->bf16, x->bf16 ----------------

__global__ void prep_bn(const float* __restrict__ gamma, const float* __restrict__ beta,
                        const float* __restrict__ mean, const float* __restrict__ var,
                        const float* __restrict__ b1,
                        float* __restrict__ colA, float* __restrict__ colB, int n) {
    int i = blockIdx.x * blockDim.x + threadIdx.x;
    if (i < n) {
        float A = gamma[i] * rsqrtf(var[i] + BN_EPS);
        colA[i] = A;
        colB[i] = beta[i] - mean[i] * A + b1[i] * A;
    }
}

// W[l][k][n] f32  ->  WT[l][n][k] bf16
__global__ void prep_wt(const float* __restrict__ W1, const float* __restrict__ W2,
                        unsigned short* __restrict__ W1T, unsigned short* __restrict__ W2T, int total) {
    int i = blockIdx.x * blockDim.x + threadIdx.x;
    if (i < total) {
        int l  = i / (DIM * DIM);
        int r  = i - l * DIM * DIM;
        int nn = r / DIM;
        int kk = r - nn * DIM;
        int sidx = l * DIM * DIM + kk * DIM + nn;
        W1T[i] = f2b(W1[sidx]);
        W2T[i] = f2b(W2[sidx]);
    }
}

__global__ void conv_x(const float* __restrict__ x, unsigned short* __restrict__ xb, int n4) {
    int i = blockIdx.x * blockDim.x + threadIdx.x;
    if (i < n4) {
        float4 v = ((const float4*)x)[i];
        unsigned lo = pack2(v.x, v.y);
        unsigned hi = pack2(v.z, v.w);
        ((uint2*)xb)[i] = make_uint2(lo, hi);
    }
}

// ---------------- gathers: 4 nodes/wave, 16 lanes/node, 16B row chunks, 4x unrolled ----------------
// One global_load_dwordx4 serves 4 different neighbor rows (one per quarter-wave);
// 4x unroll keeps 4 such loads (4KB) in flight per wave. Exec mask handles degree divergence.

__global__ __launch_bounds__(256) void gather0(const unsigned short* __restrict__ xb,
                                               const int* __restrict__ off, const int* __restrict__ deg,
                                               const uint2* __restrict__ csr,
                                               const int* __restrict__ snmask,
                                               unsigned short* __restrict__ X, int n) {
    int wave = (blockIdx.x * blockDim.x + threadIdx.x) >> 6;
    int lane = threadIdx.x & 63;
    int q    = lane >> 4;       // quarter 0..3
    int l16  = lane & 15;
    int node = wave * 4 + q;
    bool valid = node < n;
    int nd   = valid ? node : (n - 1);
    int base = off[nd];
    int dg   = valid ? deg[nd] : 0;

    float acc[8];
#pragma unroll
    for (int i = 0; i < 8; ++i) acc[i] = 0.f;

    int j = 0;
    for (; j + 4 <= dg; j += 4) {
        uint2 sw0 = csr[base + j + 0];
        uint2 sw1 = csr[base + j + 1];
        uint2 sw2 = csr[base + j + 2];
        uint2 sw3 = csr[base + j + 3];
        bf16x8 v0 = *(const bf16x8*)&xb[(long)(int)sw0.x * DIM + l16 * 8];
        bf16x8 v1 = *(const bf16x8*)&xb[(long)(int)sw1.x * DIM + l16 * 8];
        bf16x8 v2 = *(const bf16x8*)&xb[(long)(int)sw2.x * DIM + l16 * 8];
        bf16x8 v3 = *(const bf16x8*)&xb[(long)(int)sw3.x * DIM + l16 * 8];
        float w0 = __uint_as_float(sw0.y), w1 = __uint_as_float(sw1.y);
        float w2 = __uint_as_float(sw2.y), w3 = __uint_as_float(sw3.y);
#pragma unroll
        for (int i = 0; i < 8; ++i) {
            acc[i] = fmaf(w0, b2f(v0[i]), acc[i]);
            acc[i] = fmaf(w1, b2f(v1[i]), acc[i]);
            acc[i] = fmaf(w2, b2f(v2[i]), acc[i]);
            acc[i] = fmaf(w3, b2f(v3[i]), acc[i]);
        }
    }
    for (; j < dg; ++j) {
        uint2 sw = csr[base + j];
        float w  = __uint_as_float(sw.y);
        bf16x8 v = *(const bf16x8*)&xb[(long)(int)sw.x * DIM + l16 * 8];
#pragma unroll
        for (int i = 0; i < 8; ++i) acc[i] = fmaf(w, b2f(v[i]), acc[i]);
    }

    if (valid) {
        bf16x8 res = *(const bf16x8*)&xb[(long)node * DIM + l16 * 8];  // self
        if (snmask[node]) {
#pragma unroll
            for (int i = 0; i < 8; ++i) res[i] = (short)f2b(acc[i]);
        }
        *(bf16x8*)&X[(long)node * DIM + l16 * 8] = res;
    }
}

__global__ __launch_bounds__(256) void gatherL(const unsigned short* __restrict__ X,
                                               const int* __restrict__ off, const int* __restrict__ deg,
                                               const uint2* __restrict__ csr,
                                               unsigned short* __restrict__ H, int n) {
    int wave = (blockIdx.x * blockDim.x + threadIdx.x) >> 6;
    int lane = threadIdx.x & 63;
    int q    = lane >> 4;
    int l16  = lane & 15;
    int node = wave * 4 + q;
    bool valid = node < n;
    int nd   = valid ? node : (n - 1);
    int base = off[nd];
    int dg   = valid ? deg[nd] : 0;

    float acc[8];
    {   // GIN eps=0 self term
        bf16x8 self = *(const bf16x8*)&X[(long)nd * DIM + l16 * 8];
#pragma unroll
        for (int i = 0; i < 8; ++i) acc[i] = b2f(self[i]);
    }

    int j = 0;
    for (; j + 4 <= dg; j += 4) {
        uint2 sw0 = csr[base + j + 0];
        uint2 sw1 = csr[base + j + 1];
        uint2 sw2 = csr[base + j + 2];
        uint2 sw3 = csr[base + j + 3];
        bf16x8 v0 = *(const bf16x8*)&X[(long)(int)sw0.x * DIM + l16 * 8];
        bf16x8 v1 = *(const bf16x8*)&X[(long)(int)sw1.x * DIM + l16 * 8];
        bf16x8 v2 = *(const bf16x8*)&X[(long)(int)sw2.x * DIM + l16 * 8];
        bf16x8 v3 = *(const bf16x8*)&X[(long)(int)sw3.x * DIM + l16 * 8];
#pragma unroll
        for (int i = 0; i < 8; ++i)
            acc[i] += b2f(v0[i]) + b2f(v1[i]) + b2f(v2[i]) + b2f(v3[i]);
    }
    for (; j < dg; ++j) {
        uint2 sw = csr[base + j];
        bf16x8 v = *(const bf16x8*)&X[(long)(int)sw.x * DIM + l16 * 8];
#pragma unroll
        for (int i = 0; i < 8; ++i) acc[i] += b2f(v[i]);
    }

    if (valid) {
        bf16x8 res;
#pragma unroll
        for (int i = 0; i < 8; ++i) res[i] = (short)f2b(acc[i]);
        *(bf16x8*)&H[(long)node * DIM + l16 * 8] = res;
    }
}

// ---------------- MFMA MLP: H(bf16) -> Lin1+BN+ReLU -> Lin2+ReLU -> X(bf16) ----------------
// 512 threads = 8 waves. Block: 64 rows x 128 cols. Wave (wr=wid>>2, wc=wid&3): rows wr*32..+31, cols wc*32..+31.
// mfma_f32_16x16x32_bf16 layouts (gfx950, m89-verified):
//   A: lane l elem j -> A[row = l&15][k = (l>>4)*8 + j]
//   B: lane l elem j -> B[k = (l>>4)*8 + j][col = l&15]   (loaded from WT[n][k], 16B contiguous)
//   D: lane l reg  v -> D[row = (l>>4)*4 + v][col = l&15]
#define HPITCH 136   // bf16 elems; 272B rows: 16B-aligned, 2-way LDS aliasing only

__global__ __launch_bounds__(512) void mlp_mfma(const unsigned short* __restrict__ H,
                                                unsigned short* __restrict__ X,
                                                const unsigned short* __restrict__ W1T,
                                                const unsigned short* __restrict__ W2T,
                                                const float* __restrict__ colA, const float* __restrict__ colB,
                                                const float* __restrict__ b2, int n) {
    __shared__ unsigned short h_t[64 * HPITCH];
    int t    = threadIdx.x;
    int wid  = t >> 6;
    int lane = t & 63;
    int wr   = wid >> 2;          // 0..1
    int wc   = wid & 3;           // 0..3
    int c0   = wc * 32;
    int lm   = lane & 15;
    int lk   = (lane >> 4) * 8;
    int row0 = blockIdx.x * 64 + wr * 32;

    // ---- A fragments from global H (rows clamped for tail block) ----
    bf16x8 a[2][4];
#pragma unroll
    for (int rs = 0; rs < 2; ++rs)
#pragma unroll
        for (int ks = 0; ks < 4; ++ks) {
            int r = row0 + rs * 16 + lm;
            if (r >= n) r = n - 1;
            a[rs][ks] = *(const bf16x8*)&H[(long)r * DIM + ks * 32 + lk];
        }

    // ---- B fragments for W1 ----
    bf16x8 b1[2][4];
#pragma unroll
    for (int cs = 0; cs < 2; ++cs)
#pragma unroll
        for (int ks = 0; ks < 4; ++ks) {
            int col = c0 + cs * 16 + lm;
            b1[cs][ks] = *(const bf16x8*)&W1T[col * DIM + ks * 32 + lk];
        }

    f32x4 acc[2][2];
    f32x4 z = {0.f, 0.f, 0.f, 0.f};
#pragma unroll
    for (int rs = 0; rs < 2; ++rs)
#pragma unroll
        for (int cs = 0; cs < 2; ++cs) acc[rs][cs] = z;

#pragma unroll
    for (int ks = 0; ks < 4; ++ks)
#pragma unroll
        for (int rs = 0; rs < 2; ++rs)
#pragma unroll
            for (int cs = 0; cs < 2; ++cs)
                acc[rs][cs] = __builtin_amdgcn_mfma_f32_16x16x32_bf16(a[rs][ks], b1[cs][ks], acc[rs][cs], 0, 0, 0);

    // ---- epilogue 1: affine(BN)+ReLU -> bf16 -> LDS ----
#pragma unroll
    for (int rs = 0; rs < 2; ++rs)
#pragma unroll
        for (int cs = 0; cs < 2; ++cs) {
            int colv = c0 + cs * 16 + lm;
            float cA = colA[colv], cB = colB[colv];
            int rbase = wr * 32 + rs * 16 + (lane >> 4) * 4;
            f32x4 av = acc[rs][cs];
#pragma unroll
            for (int v = 0; v < 4; ++v) {
                float h = fmaxf(fmaf(av[v], cA, cB), 0.f);
                h_t[(rbase + v) * HPITCH + colv] = f2b(h);
            }
        }
    __syncthreads();

    // ---- A2 fragments from LDS, B2 fragments from global ----
    bf16x8 a2[2][4];
#pragma unroll
    for (int rs = 0; rs < 2; ++rs)
#pragma unroll
        for (int ks = 0; ks < 4; ++ks)
            a2[rs][ks] = *(const bf16x8*)&h_t[(wr * 32 + rs * 16 + lm) * HPITCH + ks * 32 + lk];

    bf16x8 b2f[2][4];
#pragma unroll
    for (int cs = 0; cs < 2; ++cs)
#pragma unroll
        for (int ks = 0; ks < 4; ++ks) {
            int col = c0 + cs * 16 + lm;
            b2f[cs][ks] = *(const bf16x8*)&W2T[col * DIM + ks * 32 + lk];
        }

#pragma unroll
    for (int rs = 0; rs < 2; ++rs)
#pragma unroll
        for (int cs = 0; cs < 2; ++cs) acc[rs][cs] = z;

#pragma unroll
    for (int ks = 0; ks < 4; ++ks)
#pragma unroll
        for (int rs = 0; rs < 2; ++rs)
#pragma unroll
            for (int cs = 0; cs < 2; ++cs)
                acc[rs][cs] = __builtin_amdgcn_mfma_f32_16x16x32_bf16(a2[rs][ks], b2f[cs][ks], acc[rs][cs], 0, 0, 0);

    __syncthreads();   // all h_t reads done before overwrite

    // ---- epilogue 2: +bias, ReLU -> bf16 -> LDS ----
#pragma unroll
    for (int rs = 0; rs < 2; ++rs)
#pragma unroll
        for (int cs = 0; cs < 2; ++cs) {
            int colv = c0 + cs * 16 + lm;
            float bb = b2[colv];
            int rbase = wr * 32 + rs * 16 + (lane >> 4) * 4;
            f32x4 av = acc[rs][cs];
#pragma unroll
            for (int v = 0; v < 4; ++v) {
                float h = fmaxf(av[v] + bb, 0.f);
                h_t[(rbase + v) * HPITCH + colv] = f2b(h);
            }
        }
    __syncthreads();

    // ---- coalesced copy-out: 64 rows, 8 threads/row, 16 elems (32B) per thread ----
    {
        int row = t >> 3;
        int ch  = (t & 7) * 16;
        int gr  = blockIdx.x * 64 + row;
        if (gr < n) {
            *(bf16x8*)&X[(long)gr * DIM + ch]     = *(const bf16x8*)&h_t[row * HPITCH + ch];
            *(bf16x8*)&X[(long)gr * DIM + ch + 8] = *(const bf16x8*)&h_t[row * HPITCH + ch + 8];
        }
    }
}

// ---------------- pool (batch sorted -> run-accumulate) ----------------

__global__ __launch_bounds__(128) void pool_kernel(const unsigned short* __restrict__ X,
                                                   const int* __restrict__ batch,
                                                   float* __restrict__ POOL, int n) {
    int c  = threadIdx.x;
    int n0 = blockIdx.x * 128;
    if (n0 >= n) return;
    int n1 = n0 + 128; if (n1 > n) n1 = n;
    int gcur = batch[n0];
    float acc = 0.f;
    for (int i = n0; i < n1; ++i) {
        int g = batch[i];
        if (g != gcur) {
            atomicAdd(&POOL[(long)gcur * DIM + c], acc);
            acc = 0.f; gcur = g;
        }
        acc += __uint_as_float(((unsigned)X[(long)i * DIM + c]) << 16);
    }
    atomicAdd(&POOL[(long)gcur * DIM + c], acc);
}

// ---------------- final head ----------------

__global__ __launch_bounds__(128) void final_mlp(const float* __restrict__ POOL,
                                                 const float* __restrict__ Wf1, const float* __restrict__ bf1,
                                                 const float* __restrict__ Wf2, const float* __restrict__ bf2,
                                                 float* __restrict__ out) {
    int g = blockIdx.x;
    int t = threadIdx.x;
    __shared__ float p[128];
    __shared__ float h[128];
    p[t] = POOL[(long)g * DIM + t];
    __syncthreads();
    float acc = bf1[t];
#pragma unroll 8
    for (int k = 0; k < DIM; ++k) acc = fmaf(p[k], Wf1[k * DIM + t], acc);
    h[t] = fmaxf(acc, 0.f);
    __syncthreads();
    if (t < NCLS) {
        float acc2 = bf2[t];
#pragma unroll 8
        for (int k = 0; k < DIM; ++k) acc2 = fmaf(h[k], Wf2[k * NCLS + t], acc2);
        out[(long)g * NCLS + t] = acc2;
    }
}

// ---------------- launch ----------------

extern "C" void kernel_launch(void* const* d_in, const int* in_sizes, int n_in,
                              void* d_out, int out_size, void* d_ws, size_t ws_size,
                              hipStream_t stream) {
    const float* x      = (const float*)d_in[0];
    const int*   ei     = (const int*)d_in[1];
    const int*   snmask = (const int*)d_in[2];
    const float* emask  = (const float*)d_in[3];
    const int*   batch  = (const int*)d_in[4];
    const float* Ws1    = (const float*)d_in[5];
    const float* bs1    = (const float*)d_in[6];
    const float* gamma  = (const float*)d_in[7];
    const float* beta   = (const float*)d_in[8];
    const float* mean   = (const float*)d_in[9];
    const float* var    = (const float*)d_in[10];
    const float* Ws2    = (const float*)d_in[11];
    const float* bs2    = (const float*)d_in[12];
    const float* Wf1    = (const float*)d_in[13];
    const float* bf1    = (const float*)d_in[14];
    const float* Wf2    = (const float*)d_in[15];
    const float* bf2    = (const float*)d_in[16];
    float* out = (float*)d_out;

    const int* srcp = ei;
    const int* dstp = ei + NEDGES;

    char* ws = (char*)d_ws;
    size_t o = 0;
    auto alloc = [&](size_t bytes) -> void* {
        void* p = ws + o;
        o = (o + bytes + 255) & ~(size_t)255;
        return p;
    };
    unsigned short* XB  = (unsigned short*)alloc((size_t)NNODES * DIM * 2);
    unsigned short* X   = (unsigned short*)alloc((size_t)NNODES * DIM * 2);
    unsigned short* H   = (unsigned short*)alloc((size_t)NNODES * DIM * 2);
    int*   deg     = (int*)alloc((size_t)NNODES * 4);
    int*   off     = (int*)alloc((size_t)NNODES * 4);
    int*   cursor  = (int*)alloc((size_t)NNODES * 4);
    int*   part    = (int*)alloc((size_t)NSB * 4);
    uint2* csr     = (uint2*)alloc((size_t)NEDGES * 8);
    float* colA    = (float*)alloc((size_t)NLAYERS * DIM * 4);
    float* colB    = (float*)alloc((size_t)NLAYERS * DIM * 4);
    unsigned short* W1T = (unsigned short*)alloc((size_t)NLAYERS * DIM * DIM * 2);
    unsigned short* W2T = (unsigned short*)alloc((size_t)NLAYERS * DIM * DIM * 2);
    float* POOL    = (float*)alloc((size_t)NGRAPH * DIM * 4);

    // deg: 50000 ints = 12500 int4; POOL: 32768 floats = 8192 int4
    zero_bufs<<<(12500 + 255) / 256, 256, 0, stream>>>((int4*)deg, 12500, (int4*)POOL, 8192);

    count_deg<<<(NEDGES + 255) / 256, 256, 0, stream>>>(dstp, deg, NEDGES);
    partial_sum<<<NSB, SCAN_BLK, 0, stream>>>(deg, part, NNODES);
    scan_partials<<<1, 256, 0, stream>>>(part, NSB);
    emit_offsets<<<NSB, SCAN_BLK, 0, stream>>>(deg, part, off, cursor, NNODES);
    fill_csr<<<(NEDGES + 255) / 256, 256, 0, stream>>>(srcp, dstp, emask, cursor, csr, NEDGES);
    prep_bn<<<(NLAYERS * DIM + 255) / 256, 256, 0, stream>>>(gamma, beta, mean, var, bs1, colA, colB, NLAYERS * DIM);
    prep_wt<<<(NLAYERS * DIM * DIM + 255) / 256, 256, 0, stream>>>(Ws1, Ws2, W1T, W2T, NLAYERS * DIM * DIM);
    conv_x<<<(NNODES * DIM / 4 + 255) / 256, 256, 0, stream>>>(x, XB, NNODES * DIM / 4);

    const int nWaves = (NNODES + 3) / 4;                       // 4 nodes per wave
    const int gatherBlocks = (nWaves * 64 + 255) / 256;
    gather0<<<gatherBlocks, 256, 0, stream>>>(XB, off, deg, csr, snmask, X, NNODES);

    const int mlpBlocks = (NNODES + 63) / 64;
    for (int l = 0; l < NLAYERS; ++l) {
        gatherL<<<gatherBlocks, 256, 0, stream>>>(X, off, deg, csr, H, NNODES);
        mlp_mfma<<<mlpBlocks, 512, 0, stream>>>(H, X,
                                                W1T + (size_t)l * DIM * DIM,
                                                W2T + (size_t)l * DIM * DIM,
                                                colA + (size_t)l * DIM,
                                                colB + (size_t)l * DIM,
                                                bs2 + (size_t)l * DIM, NNODES);
    }

    pool_kernel<<<(NNODES + 127) / 128, 128, 0, stream>>>(X, batch, POOL, NNODES);
    final_mlp<<<NGRAPH, 128, 0, stream>>>(POOL, Wf1, bf1, Wf2, bf2, out);
}

// Round 8
// 288.521 us; speedup vs baseline: 1.2297x; 1.1114x over previous
//
#include <hip/hip_runtime.h>
#include <hip/hip_bf16.h>
#include <hip/hip_fp16.h>

#define NNODES 50000
#define NEDGES 600000
#define DIM    128
#define NLAYERS 3
#define NCLS   10
#define NGRAPH 256
#define BN_EPS 1e-5f

#define SCAN_BLK 256
#define NSB ((NNODES + SCAN_BLK - 1) / SCAN_BLK)   // 196 blocks

typedef __attribute__((ext_vector_type(8))) short bf16x8;   // 8 bf16 = 4 VGPR
typedef __attribute__((ext_vector_type(4))) float f32x4;

static __device__ __forceinline__ unsigned short f2b(float f) {
    union { __hip_bfloat16 h; unsigned short u; } c;
    c.h = __float2bfloat16(f);
    return c.u;
}
static __device__ __forceinline__ float b2f(short s) {
    return __uint_as_float(((unsigned)(unsigned short)s) << 16);
}
static __device__ __forceinline__ unsigned pack2(float a, float b) {
    return (unsigned)f2b(a) | ((unsigned)f2b(b) << 16);
}

// ---------------- workspace zeroing ----------------
__global__ __launch_bounds__(256) void zero_bufs(int4* __restrict__ a, int na,
                                                 int4* __restrict__ b, int nb) {
    int i = blockIdx.x * 256 + threadIdx.x;
    int4 z = make_int4(0, 0, 0, 0);
    if (i < na) a[i] = z;
    if (i < nb) b[i] = z;
}

// ---------------- CSR build ----------------

__global__ void count_deg(const int* __restrict__ dst, int* __restrict__ deg, int E) {
    int e = blockIdx.x * blockDim.x + threadIdx.x;
    if (e < E) atomicAdd(&deg[dst[e]], 1);
}

__global__ __launch_bounds__(SCAN_BLK) void partial_sum(const int* __restrict__ deg,
                                                        int* __restrict__ part, int n) {
    int t = threadIdx.x;
    int i = blockIdx.x * SCAN_BLK + t;
    int v = (i < n) ? deg[i] : 0;
#pragma unroll
    for (int o = 32; o > 0; o >>= 1) v += __shfl_down(v, o, 64);
    __shared__ int s[SCAN_BLK / 64];
    if ((t & 63) == 0) s[t >> 6] = v;
    __syncthreads();
    if (t == 0) {
        int sum = 0;
#pragma unroll
        for (int w = 0; w < SCAN_BLK / 64; ++w) sum += s[w];
        part[blockIdx.x] = sum;
    }
}

__global__ __launch_bounds__(256) void scan_partials(int* __restrict__ part, int nb) {
    __shared__ int s[256];
    int t = threadIdx.x;
    int v = (t < nb) ? part[t] : 0;
    s[t] = v;
    __syncthreads();
    for (int o = 1; o < 256; o <<= 1) {
        int u = (t >= o) ? s[t - o] : 0;
        __syncthreads();
        s[t] += u;
        __syncthreads();
    }
    if (t < nb) part[t] = (t == 0) ? 0 : s[t - 1];
}

__global__ __launch_bounds__(SCAN_BLK) void emit_offsets(const int* __restrict__ deg,
                                                         const int* __restrict__ part,
                                                         int* __restrict__ off,
                                                         int* __restrict__ cursor, int n) {
    __shared__ int s[SCAN_BLK];
    int t = threadIdx.x;
    int i = blockIdx.x * SCAN_BLK + t;
    int v = (i < n) ? deg[i] : 0;
    s[t] = v;
    __syncthreads();
    for (int o = 1; o < SCAN_BLK; o <<= 1) {
        int u = (t >= o) ? s[t - o] : 0;
        __syncthreads();
        s[t] += u;
        __syncthreads();
    }
    if (i < n) {
        int excl = part[blockIdx.x] + s[t] - v;
        off[i] = excl;
        cursor[i] = excl;
    }
}

// 4B per edge: low16 = src (N<65536), high16 = weight as f16.
// Halves random-scatter line traffic vs 8B entries.
__global__ void fill_csr(const int* __restrict__ src, const int* __restrict__ dst,
                         const float* __restrict__ emask,
                         int* __restrict__ cursor,
                         unsigned* __restrict__ csr4, int E) {
    int e = blockIdx.x * blockDim.x + threadIdx.x;
    if (e < E) {
        int d = dst[e];
        int p = atomicAdd(&cursor[d], 1);
        unsigned wbits = (unsigned)__half_as_ushort(__float2half(emask[e]));
        csr4[p] = (unsigned)src[e] | (wbits << 16);
    }
}

// ---------------- prep: BN fold, W transpose->bf16, x->bf16 ----------------

__global__ void prep_bn(const float* __restrict__ gamma, const float* __restrict__ beta,
                        const float* __restrict__ mean, const float* __restrict__ var,
                        const float* __restrict__ b1,
                        float* __restrict__ colA, float* __restrict__ colB, int n) {
    int i = blockIdx.x * blockDim.x + threadIdx.x;
    if (i < n) {
        float A = gamma[i] * rsqrtf(var[i] + BN_EPS);
        colA[i] = A;
        colB[i] = beta[i] - mean[i] * A + b1[i] * A;
    }
}

// W[l][k][n] f32  ->  WT[l][n][k] bf16
__global__ void prep_wt(const float* __restrict__ W1, const float* __restrict__ W2,
                        unsigned short* __restrict__ W1T, unsigned short* __restrict__ W2T, int total) {
    int i = blockIdx.x * blockDim.x + threadIdx.x;
    if (i < total) {
        int l  = i / (DIM * DIM);
        int r  = i - l * DIM * DIM;
        int nn = r / DIM;
        int kk = r - nn * DIM;
        int sidx = l * DIM * DIM + kk * DIM + nn;
        W1T[i] = f2b(W1[sidx]);
        W2T[i] = f2b(W2[sidx]);
    }
}

__global__ void conv_x(const float* __restrict__ x, unsigned short* __restrict__ xb, int n4) {
    int i = blockIdx.x * blockDim.x + threadIdx.x;
    if (i < n4) {
        float4 v = ((const float4*)x)[i];
        unsigned lo = pack2(v.x, v.y);
        unsigned hi = pack2(v.z, v.w);
        ((uint2*)xb)[i] = make_uint2(lo, hi);
    }
}

// ---------------- gather0: weighted SimpleConv + supernode select ----------------
// 4 nodes/wave, 16 lanes/node, 16B row chunks, 4x unrolled.

__global__ __launch_bounds__(256) void gather0(const unsigned short* __restrict__ xb,
                                               const int* __restrict__ off, const int* __restrict__ deg,
                                               const unsigned* __restrict__ csr4,
                                               const int* __restrict__ snmask,
                                               unsigned short* __restrict__ X, int n) {
    int wave = (blockIdx.x * blockDim.x + threadIdx.x) >> 6;
    int lane = threadIdx.x & 63;
    int q    = lane >> 4;       // quarter 0..3
    int l16  = lane & 15;
    int node = wave * 4 + q;
    bool valid = node < n;
    int nd   = valid ? node : (n - 1);
    int base = off[nd];
    int dg   = valid ? deg[nd] : 0;

    float acc[8];
#pragma unroll
    for (int i = 0; i < 8; ++i) acc[i] = 0.f;

    int j = 0;
    for (; j + 4 <= dg; j += 4) {
        unsigned c0 = csr4[base + j + 0];
        unsigned c1 = csr4[base + j + 1];
        unsigned c2 = csr4[base + j + 2];
        unsigned c3 = csr4[base + j + 3];
        bf16x8 v0 = *(const bf16x8*)&xb[(long)(c0 & 0xffffu) * DIM + l16 * 8];
        bf16x8 v1 = *(const bf16x8*)&xb[(long)(c1 & 0xffffu) * DIM + l16 * 8];
        bf16x8 v2 = *(const bf16x8*)&xb[(long)(c2 & 0xffffu) * DIM + l16 * 8];
        bf16x8 v3 = *(const bf16x8*)&xb[(long)(c3 & 0xffffu) * DIM + l16 * 8];
        float w0 = __half2float(__ushort_as_half((unsigned short)(c0 >> 16)));
        float w1 = __half2float(__ushort_as_half((unsigned short)(c1 >> 16)));
        float w2 = __half2float(__ushort_as_half((unsigned short)(c2 >> 16)));
        float w3 = __half2float(__ushort_as_half((unsigned short)(c3 >> 16)));
#pragma unroll
        for (int i = 0; i < 8; ++i) {
            acc[i] = fmaf(w0, b2f(v0[i]), acc[i]);
            acc[i] = fmaf(w1, b2f(v1[i]), acc[i]);
            acc[i] = fmaf(w2, b2f(v2[i]), acc[i]);
            acc[i] = fmaf(w3, b2f(v3[i]), acc[i]);
        }
    }
    for (; j < dg; ++j) {
        unsigned c = csr4[base + j];
        float w = __half2float(__ushort_as_half((unsigned short)(c >> 16)));
        bf16x8 v = *(const bf16x8*)&xb[(long)(c & 0xffffu) * DIM + l16 * 8];
#pragma unroll
        for (int i = 0; i < 8; ++i) acc[i] = fmaf(w, b2f(v[i]), acc[i]);
    }

    if (valid) {
        bf16x8 res = *(const bf16x8*)&xb[(long)node * DIM + l16 * 8];  // self
        if (snmask[node]) {
#pragma unroll
            for (int i = 0; i < 8; ++i) res[i] = (short)f2b(acc[i]);
        }
        *(bf16x8*)&X[(long)node * DIM + l16 * 8] = res;
    }
}

// ---------------- fused GIN layer: gather(LDS) -> Lin1+BN+ReLU -> Lin2+ReLU ----------------
// 512 threads = 8 waves, 64 rows/block.
// Gather: wave w gathers rows w*8..w*8+7 (2 rounds of quarter-wave x 4 nodes) into h_in LDS.
// GEMM: wave (wr=wid>>2, wc=wid&3) computes rows wr*32..+31, cols wc*32..+31.
// mfma_f32_16x16x32_bf16 layouts (gfx950, m89-verified):
//   A: lane l elem j -> A[row = l&15][k = (l>>4)*8 + j]
//   B: lane l elem j -> B[k = (l>>4)*8 + j][col = l&15]   (from WT[n][k], 16B contiguous)
//   D: lane l reg  v -> D[row = (l>>4)*4 + v][col = l&15]
#define HPITCH 136   // bf16 elems; 272B rows: 16B-aligned, 2-way LDS aliasing only

__global__ __launch_bounds__(512) void gin_layer(const unsigned short* __restrict__ Xin,
                                                 unsigned short* __restrict__ Xout,
                                                 const int* __restrict__ off, const int* __restrict__ deg,
                                                 const unsigned* __restrict__ csr4,
                                                 const unsigned short* __restrict__ W1T,
                                                 const unsigned short* __restrict__ W2T,
                                                 const float* __restrict__ colA, const float* __restrict__ colB,
                                                 const float* __restrict__ b2, int n) {
    __shared__ unsigned short h_in[64 * HPITCH];
    __shared__ unsigned short h_t[64 * HPITCH];
    int t    = threadIdx.x;
    int wid  = t >> 6;
    int lane = t & 63;
    int q    = lane >> 4;
    int l16  = lane & 15;
    int lm   = lane & 15;
    int lk   = (lane >> 4) * 8;
    int wr   = wid >> 2;          // 0..1
    int wc   = wid & 3;           // 0..3
    int c0   = wc * 32;
    int row0 = blockIdx.x * 64;

    // ---- W1 B-fragments first: global weight fetch overlaps gather latency ----
    bf16x8 b1[2][4];
#pragma unroll
    for (int cs = 0; cs < 2; ++cs)
#pragma unroll
        for (int ks = 0; ks < 4; ++ks) {
            int col = c0 + cs * 16 + lm;
            b1[cs][ks] = *(const bf16x8*)&W1T[col * DIM + ks * 32 + lk];
        }

    // ---- gather phase: GIN eps=0 agg (self + neighbor sum) into h_in ----
#pragma unroll
    for (int rnd = 0; rnd < 2; ++rnd) {
        int lrow = wid * 8 + rnd * 4 + q;
        int node = row0 + lrow;
        bool valid = node < n;
        int nd   = valid ? node : (n - 1);
        int base = off[nd];
        int dg   = valid ? deg[nd] : 0;

        float acc[8];
        {
            bf16x8 self = *(const bf16x8*)&Xin[(long)nd * DIM + l16 * 8];
#pragma unroll
            for (int i = 0; i < 8; ++i) acc[i] = b2f(self[i]);
        }
        int j = 0;
        for (; j + 4 <= dg; j += 4) {
            unsigned e0 = csr4[base + j + 0];
            unsigned e1 = csr4[base + j + 1];
            unsigned e2 = csr4[base + j + 2];
            unsigned e3 = csr4[base + j + 3];
            bf16x8 v0 = *(const bf16x8*)&Xin[(long)(e0 & 0xffffu) * DIM + l16 * 8];
            bf16x8 v1 = *(const bf16x8*)&Xin[(long)(e1 & 0xffffu) * DIM + l16 * 8];
            bf16x8 v2 = *(const bf16x8*)&Xin[(long)(e2 & 0xffffu) * DIM + l16 * 8];
            bf16x8 v3 = *(const bf16x8*)&Xin[(long)(e3 & 0xffffu) * DIM + l16 * 8];
#pragma unroll
            for (int i = 0; i < 8; ++i)
                acc[i] += b2f(v0[i]) + b2f(v1[i]) + b2f(v2[i]) + b2f(v3[i]);
        }
        for (; j < dg; ++j) {
            unsigned e = csr4[base + j];
            bf16x8 v = *(const bf16x8*)&Xin[(long)(e & 0xffffu) * DIM + l16 * 8];
#pragma unroll
            for (int i = 0; i < 8; ++i) acc[i] += b2f(v[i]);
        }
        bf16x8 r;
#pragma unroll
        for (int i = 0; i < 8; ++i) r[i] = valid ? (short)f2b(acc[i]) : (short)0;
        *(bf16x8*)&h_in[lrow * HPITCH + l16 * 8] = r;
    }
    __syncthreads();

    // ---- GEMM1: A from h_in LDS ----
    bf16x8 a[2][4];
#pragma unroll
    for (int rs = 0; rs < 2; ++rs)
#pragma unroll
        for (int ks = 0; ks < 4; ++ks)
            a[rs][ks] = *(const bf16x8*)&h_in[(wr * 32 + rs * 16 + lm) * HPITCH + ks * 32 + lk];

    f32x4 acc[2][2];
    f32x4 z = {0.f, 0.f, 0.f, 0.f};
#pragma unroll
    for (int rs = 0; rs < 2; ++rs)
#pragma unroll
        for (int cs = 0; cs < 2; ++cs) acc[rs][cs] = z;

#pragma unroll
    for (int ks = 0; ks < 4; ++ks)
#pragma unroll
        for (int rs = 0; rs < 2; ++rs)
#pragma unroll
            for (int cs = 0; cs < 2; ++cs)
                acc[rs][cs] = __builtin_amdgcn_mfma_f32_16x16x32_bf16(a[rs][ks], b1[cs][ks], acc[rs][cs], 0, 0, 0);

    // ---- epilogue 1: affine(BN)+ReLU -> bf16 -> h_t ----
#pragma unroll
    for (int rs = 0; rs < 2; ++rs)
#pragma unroll
        for (int cs = 0; cs < 2; ++cs) {
            int colv = c0 + cs * 16 + lm;
            float cA = colA[colv], cB = colB[colv];
            int rbase = wr * 32 + rs * 16 + (lane >> 4) * 4;
            f32x4 av = acc[rs][cs];
#pragma unroll
            for (int v = 0; v < 4; ++v) {
                float h = fmaxf(fmaf(av[v], cA, cB), 0.f);
                h_t[(rbase + v) * HPITCH + colv] = f2b(h);
            }
        }
    __syncthreads();

    // ---- GEMM2: A from h_t LDS, B from global W2T ----
    bf16x8 a2[2][4];
#pragma unroll
    for (int rs = 0; rs < 2; ++rs)
#pragma unroll
        for (int ks = 0; ks < 4; ++ks)
            a2[rs][ks] = *(const bf16x8*)&h_t[(wr * 32 + rs * 16 + lm) * HPITCH + ks * 32 + lk];

    bf16x8 b2f_[2][4];
#pragma unroll
    for (int cs = 0; cs < 2; ++cs)
#pragma unroll
        for (int ks = 0; ks < 4; ++ks) {
            int col = c0 + cs * 16 + lm;
            b2f_[cs][ks] = *(const bf16x8*)&W2T[col * DIM + ks * 32 + lk];
        }

#pragma unroll
    for (int rs = 0; rs < 2; ++rs)
#pragma unroll
        for (int cs = 0; cs < 2; ++cs) acc[rs][cs] = z;

#pragma unroll
    for (int ks = 0; ks < 4; ++ks)
#pragma unroll
        for (int rs = 0; rs < 2; ++rs)
#pragma unroll
            for (int cs = 0; cs < 2; ++cs)
                acc[rs][cs] = __builtin_amdgcn_mfma_f32_16x16x32_bf16(a2[rs][ks], b2f_[cs][ks], acc[rs][cs], 0, 0, 0);

    __syncthreads();   // all h_t reads done before overwrite

    // ---- epilogue 2: +bias, ReLU -> bf16 -> h_t ----
#pragma unroll
    for (int rs = 0; rs < 2; ++rs)
#pragma unroll
        for (int cs = 0; cs < 2; ++cs) {
            int colv = c0 + cs * 16 + lm;
            float bb = b2[colv];
            int rbase = wr * 32 + rs * 16 + (lane >> 4) * 4;
            f32x4 av = acc[rs][cs];
#pragma unroll
            for (int v = 0; v < 4; ++v) {
                float h = fmaxf(av[v] + bb, 0.f);
                h_t[(rbase + v) * HPITCH + colv] = f2b(h);
            }
        }
    __syncthreads();

    // ---- coalesced copy-out: 64 rows, 8 threads/row, 32B per thread ----
    {
        int row = t >> 3;
        int ch  = (t & 7) * 16;
        int gr  = row0 + row;
        if (gr < n) {
            *(bf16x8*)&Xout[(long)gr * DIM + ch]     = *(const bf16x8*)&h_t[row * HPITCH + ch];
            *(bf16x8*)&Xout[(long)gr * DIM + ch + 8] = *(const bf16x8*)&h_t[row * HPITCH + ch + 8];
        }
    }
}

// ---------------- pool (batch sorted -> run-accumulate) ----------------

__global__ __launch_bounds__(128) void pool_kernel(const unsigned short* __restrict__ X,
                                                   const int* __restrict__ batch,
                                                   float* __restrict__ POOL, int n) {
    int c  = threadIdx.x;
    int n0 = blockIdx.x * 128;
    if (n0 >= n) return;
    int n1 = n0 + 128; if (n1 > n) n1 = n;
    int gcur = batch[n0];
    float acc = 0.f;
    for (int i = n0; i < n1; ++i) {
        int g = batch[i];
        if (g != gcur) {
            atomicAdd(&POOL[(long)gcur * DIM + c], acc);
            acc = 0.f; gcur = g;
        }
        acc += __uint_as_float(((unsigned)X[(long)i * DIM + c]) << 16);
    }
    atomicAdd(&POOL[(long)gcur * DIM + c], acc);
}

// ---------------- final head ----------------

__global__ __launch_bounds__(128) void final_mlp(const float* __restrict__ POOL,
                                                 const float* __restrict__ Wf1, const float* __restrict__ bf1,
                                                 const float* __restrict__ Wf2, const float* __restrict__ bf2,
                                                 float* __restrict__ out) {
    int g = blockIdx.x;
    int t = threadIdx.x;
    __shared__ float p[128];
    __shared__ float h[128];
    p[t] = POOL[(long)g * DIM + t];
    __syncthreads();
    float acc = bf1[t];
#pragma unroll 8
    for (int k = 0; k < DIM; ++k) acc = fmaf(p[k], Wf1[k * DIM + t], acc);
    h[t] = fmaxf(acc, 0.f);
    __syncthreads();
    if (t < NCLS) {
        float acc2 = bf2[t];
#pragma unroll 8
        for (int k = 0; k < DIM; ++k) acc2 = fmaf(h[k], Wf2[k * NCLS + t], acc2);
        out[(long)g * NCLS + t] = acc2;
    }
}

// ---------------- launch ----------------

extern "C" void kernel_launch(void* const* d_in, const int* in_sizes, int n_in,
                              void* d_out, int out_size, void* d_ws, size_t ws_size,
                              hipStream_t stream) {
    const float* x      = (const float*)d_in[0];
    const int*   ei     = (const int*)d_in[1];
    const int*   snmask = (const int*)d_in[2];
    const float* emask  = (const float*)d_in[3];
    const int*   batch  = (const int*)d_in[4];
    const float* Ws1    = (const float*)d_in[5];
    const float* bs1    = (const float*)d_in[6];
    const float* gamma  = (const float*)d_in[7];
    const float* beta   = (const float*)d_in[8];
    const float* mean   = (const float*)d_in[9];
    const float* var    = (const float*)d_in[10];
    const float* Ws2    = (const float*)d_in[11];
    const float* bs2    = (const float*)d_in[12];
    const float* Wf1    = (const float*)d_in[13];
    const float* bf1    = (const float*)d_in[14];
    const float* Wf2    = (const float*)d_in[15];
    const float* bf2    = (const float*)d_in[16];
    float* out = (float*)d_out;

    const int* srcp = ei;
    const int* dstp = ei + NEDGES;

    char* ws = (char*)d_ws;
    size_t o = 0;
    auto alloc = [&](size_t bytes) -> void* {
        void* p = ws + o;
        o = (o + bytes + 255) & ~(size_t)255;
        return p;
    };
    unsigned short* XB  = (unsigned short*)alloc((size_t)NNODES * DIM * 2);
    unsigned short* X   = (unsigned short*)alloc((size_t)NNODES * DIM * 2);
    unsigned short* H   = (unsigned short*)alloc((size_t)NNODES * DIM * 2);
    int*   deg     = (int*)alloc((size_t)NNODES * 4);
    int*   off     = (int*)alloc((size_t)NNODES * 4);
    int*   cursor  = (int*)alloc((size_t)NNODES * 4);
    int*   part    = (int*)alloc((size_t)NSB * 4);
    unsigned* csr4 = (unsigned*)alloc((size_t)NEDGES * 4);
    float* colA    = (float*)alloc((size_t)NLAYERS * DIM * 4);
    float* colB    = (float*)alloc((size_t)NLAYERS * DIM * 4);
    unsigned short* W1T = (unsigned short*)alloc((size_t)NLAYERS * DIM * DIM * 2);
    unsigned short* W2T = (unsigned short*)alloc((size_t)NLAYERS * DIM * DIM * 2);
    float* POOL    = (float*)alloc((size_t)NGRAPH * DIM * 4);

    // deg: 50000 ints = 12500 int4; POOL: 32768 floats = 8192 int4
    zero_bufs<<<(12500 + 255) / 256, 256, 0, stream>>>((int4*)deg, 12500, (int4*)POOL, 8192);

    count_deg<<<(NEDGES + 255) / 256, 256, 0, stream>>>(dstp, deg, NEDGES);
    partial_sum<<<NSB, SCAN_BLK, 0, stream>>>(deg, part, NNODES);
    scan_partials<<<1, 256, 0, stream>>>(part, NSB);
    emit_offsets<<<NSB, SCAN_BLK, 0, stream>>>(deg, part, off, cursor, NNODES);
    fill_csr<<<(NEDGES + 255) / 256, 256, 0, stream>>>(srcp, dstp, emask, cursor, csr4, NEDGES);
    prep_bn<<<(NLAYERS * DIM + 255) / 256, 256, 0, stream>>>(gamma, beta, mean, var, bs1, colA, colB, NLAYERS * DIM);
    prep_wt<<<(NLAYERS * DIM * DIM + 255) / 256, 256, 0, stream>>>(Ws1, Ws2, W1T, W2T, NLAYERS * DIM * DIM);
    conv_x<<<(NNODES * DIM / 4 + 255) / 256, 256, 0, stream>>>(x, XB, NNODES * DIM / 4);

    const int nWaves = (NNODES + 3) / 4;                       // 4 nodes per wave
    const int gatherBlocks = (nWaves * 64 + 255) / 256;
    gather0<<<gatherBlocks, 256, 0, stream>>>(XB, off, deg, csr4, snmask, X, NNODES);

    // ping-pong: X -> H -> X -> H  (gin_layer reads random rows globally, so no in-place)
    const unsigned short* bufs[4] = {X, H, X, H};
    const int layerBlocks = (NNODES + 63) / 64;
    for (int l = 0; l < NLAYERS; ++l) {
        gin_layer<<<layerBlocks, 512, 0, stream>>>((const unsigned short*)bufs[l],
                                                   (unsigned short*)bufs[l + 1],
                                                   off, deg, csr4,
                                                   W1T + (size_t)l * DIM * DIM,
                                                   W2T + (size_t)l * DIM * DIM,
                                                   colA + (size_t)l * DIM,
                                                   colB + (size_t)l * DIM,
                                                   bs2 + (size_t)l * DIM, NNODES);
    }

    pool_kernel<<<(NNODES + 127) / 128, 128, 0, stream>>>(H, batch, POOL, NNODES);
    final_mlp<<<NGRAPH, 128, 0, stream>>>(POOL, Wf1, bf1, Wf2, bf2, out);
}